// Round 7
// baseline (405.653 us; speedup 1.0000x reference)
//
#include <hip/hip_runtime.h>
#include <hip/hip_bf16.h>

// y = (fq_per_token(x) @ fq_per_channel(w)^T) + b
// Exact int8 factorization: y[m,n] = sx[m]*sw[n]*dot_i32(qx[m,:],qw[n,:]) + b[n]

#define K_DIM 4096
#define N_DIM 4096
#define NT (K_DIM / 64)    // 64 K-tiles of 64 bytes

typedef int v4i __attribute__((ext_vector_type(4)));

__device__ __forceinline__ void cp16(void* lds, const void* g) {
    __builtin_amdgcn_global_load_lds(
        (const __attribute__((address_space(1))) void*)g,
        (__attribute__((address_space(3))) void*)lds, 16, 0, 0);
}

// ---------------------------------------------------------------------------
// Per-row symmetric int8 fake-quant, x and w merged into one grid. UNCHANGED
// (round-6 recip version; total was insensitive -> quant not VALU-bound).
// ---------------------------------------------------------------------------
__global__ __launch_bounds__(256) void quant_rows_kernel(
    const float* __restrict__ x, const float* __restrict__ w, int M,
    char* __restrict__ qx, char* __restrict__ qw,
    float* __restrict__ sx, float* __restrict__ sw) {
    const int blk = blockIdx.x;
    const bool is_x = blk < M;
    const int row = is_x ? blk : blk - M;
    const float* rp = (is_x ? x : w) + (size_t)row * 4096;
    char* qdst = is_x ? qx : qw;
    float* sdst = is_x ? sx : sw;

    const int tid = threadIdx.x;

    float4 v[4];
#pragma unroll
    for (int i = 0; i < 4; ++i)
        v[i] = *(const float4*)(rp + 4 * (tid + 256 * i));

    float m = 0.0f;
#pragma unroll
    for (int i = 0; i < 4; ++i) {
        m = fmaxf(m, fmaxf(fmaxf(fabsf(v[i].x), fabsf(v[i].y)),
                           fmaxf(fabsf(v[i].z), fabsf(v[i].w))));
    }
#pragma unroll
    for (int off = 32; off > 0; off >>= 1)
        m = fmaxf(m, __shfl_down(m, off));

    __shared__ float red[4];
    if ((tid & 63) == 0) red[tid >> 6] = m;
    __syncthreads();
    const float amax = fmaxf(fmaxf(red[0], red[1]), fmaxf(red[2], red[3]));
    const float scale = fmaxf(amax / 127.0f, 1e-8f);
    const float qs = 1.0f / scale;

    int* qout = (int*)(qdst + (size_t)row * 4096);
#pragma unroll
    for (int i = 0; i < 4; ++i) {
        int q0 = (int)fminf(fmaxf(rintf(v[i].x * qs), -128.0f), 127.0f);
        int q1 = (int)fminf(fmaxf(rintf(v[i].y * qs), -128.0f), 127.0f);
        int q2 = (int)fminf(fmaxf(rintf(v[i].z * qs), -128.0f), 127.0f);
        int q3 = (int)fminf(fmaxf(rintf(v[i].w * qs), -128.0f), 127.0f);
        qout[tid + 256 * i] =
            (q0 & 255) | ((q1 & 255) << 8) | ((q2 & 255) << 16) | ((q3 & 255) << 24);
    }
    if (tid == 0) sdst[row] = scale;
}

// ---------------------------------------------------------------------------
// int8 GEMM. Round-7 change: 2 BLOCKS PER CU (independent barrier domains).
//
// Evidence from rounds 1-6: every schedule of the 256^2/8-wave/1-block-CU
// config lands at ~5021 cy/K-tile = LDS-read window (1152 cy per k-step,
// CU-wide) SERIAL with MFMA window (1306 cy per k-step, per SIMD). The
// serializer: in-order issue (a wave can't issue k-step i+1 reads before
// issuing all k-step i MFMAs; a 2nd fragment reg set doesn't fit 256 VGPR)
// plus a single barrier domain (all 8 waves phase-locked at every barrier;
// stagger r6 changed data, not timing -> null). Fix: two INDEPENDENT blocks
// per CU drift naturally -> block A reads LDS while block B MFMAs (m114
// implicit overlap, the mechanism m97 used at ~3 blocks/CU).
//
// Config: 128(M) x 256(N) tile, 256 thr = 4 waves (1x4 along N), per-wave
// output 128x64 (identical per-wave arithmetic to rounds 1-6: 12 ds_read +
// 32 MFMA per 64B k-step). BK=64. LDS = 2 parities x (A 8KB + B 16KB) =
// 48 KiB -> 2 blocks/CU (96 KiB of 160). Free-run loop (r5 structure):
// [BAR] stage t+1 -> par^1 (6 cp16) ; 12 ds_read ; 32 MFMA ; vmcnt(0) [BAR].
//   RAW: reads of par hit data staged in t-1, drained by t-1's vmcnt(0).
//   WAR: stage writes par^1, last read in t-1 and consumed by t-1's MFMAs
//        (data dep) before t-1's closing barrier.
//   vmcnt(0): only in-flight loads are t+1's 6 stages, issued one full tile
//        (~2500 cy) earlier, needed right after the barrier -> ~free.
//
// Swizzle re-derived for 64B rows (4 x 16B chunks, bank-group = addr/16
// mod 8 = (4*row + pos) mod 8): store chunk c of row r at pos c^((r>>1)&3);
// read pos = lg ^ ((ln>>1)&3). Every 8-lane b128 service group hits 8
// distinct bank-groups (verified r0..7: {0,4,1,5,2,6,3,7}) -> conflict-free.
// Source pre-swizzled, LDS dest linear (global_load_lds requirement).
// ---------------------------------------------------------------------------
__global__ __launch_bounds__(256, 2) void gemm_i8_kernel(
    const char* __restrict__ qx, const char* __restrict__ qw,
    const float* __restrict__ sx, const float* __restrict__ sw,
    const float* __restrict__ bias, float* __restrict__ y) {

    __shared__ __align__(16) char lds[49152];   // 2 x 24576

    const int tid  = threadIdx.x;
    const int wave = tid >> 6;
    const int lane = tid & 63;
    const int ln   = lane & 15;   // MFMA row/col index
    const int lg   = lane >> 4;   // MFMA lane-group 0..3 (k-chunk)
    const int wn   = wave;        // wave tile n (0..3) -> cols wn*64..+63

    const int bm = blockIdx.y;    // M-tile (128 rows)
    const int bn = blockIdx.x;    // N-tile (256 cols)

    // ---- staging precompute: A = 512 chunks (2/thread), B = 1024 (4/thread)
    // LDS chunk ci -> row = ci>>2, pos = ci&3, global chunk = pos^((row>>1)&3)
    const char* aSrc[2]; int aDst[2];
#pragma unroll
    for (int j = 0; j < 2; ++j) {
        const int ci = tid + 256 * j, row = ci >> 2, pos = ci & 3;
        const int sc = pos ^ ((row >> 1) & 3);
        aSrc[j] = qx + (size_t)(bm * 128 + row) * K_DIM + sc * 16;
        aDst[j] = ci * 16;
    }
    const char* bSrc[4]; int bDst[4];
#pragma unroll
    for (int j = 0; j < 4; ++j) {
        const int ci = tid + 256 * j, row = ci >> 2, pos = ci & 3;
        const int sc = pos ^ ((row >> 1) & 3);
        bSrc[j] = qw + (size_t)(bn * 256 + row) * K_DIM + sc * 16;
        bDst[j] = 8192 + ci * 16;
    }

#define PAR_SZ 24576
#define STAGE(par, t) do {                                                   \
    _Pragma("unroll")                                                        \
    for (int j = 0; j < 2; ++j)                                              \
        cp16(lds + (par) * PAR_SZ + aDst[j], aSrc[j] + (size_t)(t) * 64);    \
    _Pragma("unroll")                                                        \
    for (int j = 0; j < 4; ++j)                                              \
        cp16(lds + (par) * PAR_SZ + bDst[j], bSrc[j] + (size_t)(t) * 64);    \
    } while (0)

#define BAR()   __builtin_amdgcn_s_barrier()
#define FENCE() asm volatile("" ::: "memory")

    // ---- fragment read offsets: logical k-chunk lg of row r at swizzled pos
    const int chByte = (lg ^ ((ln >> 1) & 3)) * 16;
    int aOff[8], bOff[4];
#pragma unroll
    for (int mt = 0; mt < 8; ++mt) aOff[mt] = (mt * 16 + ln) * 64 + chByte;
#pragma unroll
    for (int nt = 0; nt < 4; ++nt)
        bOff[nt] = 8192 + (wn * 64 + nt * 16 + ln) * 64 + chByte;

    v4i acc[8][4] = {};

    // ---- prologue: stage tile 0, drain, barrier
    STAGE(0, 0);
    asm volatile("s_waitcnt vmcnt(0)" ::: "memory");
    BAR(); FENCE();

    for (int t = 0; t < NT; ++t) {
        const int par  = t & 1;
        const int base = par * PAR_SZ;

        if (t + 1 < NT) STAGE(par ^ 1, t + 1);

        v4i afr[8], bfr[4];
#pragma unroll
        for (int m = 0; m < 8; ++m)
            afr[m] = *(const v4i*)(lds + base + aOff[m]);
#pragma unroll
        for (int n = 0; n < 4; ++n)
            bfr[n] = *(const v4i*)(lds + base + bOff[n]);
        __builtin_amdgcn_s_setprio(1);
#pragma unroll
        for (int m = 0; m < 8; ++m)
#pragma unroll
            for (int n = 0; n < 4; ++n)
                acc[m][n] = __builtin_amdgcn_mfma_i32_16x16x64_i8(
                    afr[m], bfr[n], acc[m][n], 0, 0, 0);
        __builtin_amdgcn_s_setprio(0);

        asm volatile("s_waitcnt vmcnt(0)" ::: "memory");
        BAR(); FENCE();
    }

    // ---- epilogue (proven). C/D (16x16): col = lane&15, row = lg*4 + reg.
    const int m_base = bm * 128;
    const int n_base = bn * 256 + wn * 64;

    float sxr[8][4];
#pragma unroll
    for (int m = 0; m < 8; ++m)
#pragma unroll
        for (int r = 0; r < 4; ++r)
            sxr[m][r] = sx[m_base + m * 16 + lg * 4 + r];

#pragma unroll
    for (int n = 0; n < 4; ++n) {
        const int col = n_base + n * 16 + ln;
        const float swv = sw[col];
        const float bv  = bias[col];
#pragma unroll
        for (int m = 0; m < 8; ++m) {
            const int row = m_base + m * 16 + lg * 4;
#pragma unroll
            for (int r = 0; r < 4; ++r) {
                y[(size_t)(row + r) * N_DIM + col] =
                    (float)acc[m][n][r] * sxr[m][r] * swv + bv;
            }
        }
    }
#undef PAR_SZ
#undef STAGE
#undef BAR
#undef FENCE
}

extern "C" void kernel_launch(void* const* d_in, const int* in_sizes, int n_in,
                              void* d_out, int out_size, void* d_ws, size_t ws_size,
                              hipStream_t stream) {
    const float* x = (const float*)d_in[0];   // [B*S, 4096] = [8192, 4096]
    const float* w = (const float*)d_in[1];   // [4096, 4096]
    const float* b = (const float*)d_in[2];   // [4096]
    float* y = (float*)d_out;                 // [8192, 4096]

    const int M = in_sizes[0] / K_DIM;        // 8192
    const int O = in_sizes[1] / K_DIM;        // 4096

    // Workspace layout
    char* qx = (char*)d_ws;                           // M*4096 int8
    char* qw = qx + (size_t)M * K_DIM;                // O*4096 int8
    float* sx = (float*)(qw + (size_t)O * K_DIM);     // M floats
    float* sw = sx + M;                               // O floats

    quant_rows_kernel<<<M + O, 256, 0, stream>>>(x, w, M, qx, qw, sx, sw);

    dim3 grid(N_DIM / 256, M / 128);                  // (16, 64) = 1024 blocks
    gemm_i8_kernel<<<grid, 256, 0, stream>>>(qx, qw, sx, sw, b, y);
}